// Round 15
// baseline (294.990 us; speedup 1.0000x reference)
//
#include <hip/hip_runtime.h>
#include <math.h>

#define INDIM 256
#define HID 128
#define HEADS 4
#define NGAT 3
#define LN_EPS 1e-5f
#define SLOPE 0.2f
#define MPAD 40064  // 313 * 128; N=40000 is divisible by 16
#define LOG2E 1.4426950408889634f

typedef __attribute__((ext_vector_type(8))) short short8;
typedef __attribute__((ext_vector_type(4))) float f32x4;

__device__ inline float wsum(float v) {
#pragma unroll
  for (int m = 1; m < 64; m <<= 1) v += __shfl_xor(v, m, 64);
  return v;
}
__device__ inline float wmax(float v) {
#pragma unroll
  for (int m = 1; m < 64; m <<= 1) v = fmaxf(v, __shfl_xor(v, m, 64));
  return v;
}
// leaky_relu then scale to exp2 domain
__device__ inline float lk2(float v) { return fmaxf(v, SLOPE * v) * LOG2E; }
// static-select (broadcast BEFORE select — round-5 lesson)
__device__ inline float sel4(float a0, float a1, float a2, float a3, int i) {
  float lo = (i & 1) ? a1 : a0;
  float hi = (i & 1) ? a3 : a2;
  return (i & 2) ? hi : lo;
}

__device__ inline unsigned short f2b(float f) {
  unsigned u = __float_as_uint(f);
  unsigned r = (u + 0x7FFFu + ((u >> 16) & 1u)) >> 16;
  return (unsigned short)r;
}
__device__ inline float b2f(unsigned short b) {
  return __uint_as_float(((unsigned)b) << 16);
}
__device__ inline void unp8(const uint4 v, float f[8]) {
  f[0] = __uint_as_float(v.x << 16);
  f[1] = __uint_as_float(v.x & 0xFFFF0000u);
  f[2] = __uint_as_float(v.y << 16);
  f[3] = __uint_as_float(v.y & 0xFFFF0000u);
  f[4] = __uint_as_float(v.z << 16);
  f[5] = __uint_as_float(v.z & 0xFFFF0000u);
  f[6] = __uint_as_float(v.w << 16);
  f[7] = __uint_as_float(v.w & 0xFFFF0000u);
}

// MFMA fragment layout index: element (row,k) of a [rows][K] bf16 matrix.
__device__ __host__ inline size_t fidx(int row, int k, int K) {
  return ((size_t)(row >> 4) * (K >> 5) + (k >> 5)) * 512 +
         ((((k >> 3) & 3) * 16 + (row & 15)) << 3) + (k & 7);
}

// ---------------- CSR construction ----------------
__global__ void k_deg(const int* __restrict__ ei, int E, int N, int* __restrict__ deg) {
  int e = blockIdx.x * blockDim.x + threadIdx.x;
  if (e >= E + N) return;
  int dst = (e < E) ? ei[E + e] : (e - E);
  atomicAdd(&deg[dst], 1);
}

__global__ void k_scan1(const int* __restrict__ deg, int N, int* __restrict__ bsums) {
  __shared__ int s[256];
  int gid = blockIdx.x * 256 + threadIdx.x;
  s[threadIdx.x] = (gid < N) ? deg[gid] : 0;
  __syncthreads();
  for (int off = 128; off > 0; off >>= 1) {
    if (threadIdx.x < off) s[threadIdx.x] += s[threadIdx.x + off];
    __syncthreads();
  }
  if (threadIdx.x == 0) bsums[blockIdx.x] = s[0];
}

// one-block parallel scan over block sums (nblk <= 256)
__global__ void k_scan2(int* __restrict__ bsums, int nblk, int* __restrict__ rowptr, int N) {
  __shared__ int s[256];
  int t = threadIdx.x;
  int v = (t < nblk) ? bsums[t] : 0;
  s[t] = v;
  __syncthreads();
  for (int off = 1; off < 256; off <<= 1) {
    int u = (t >= off) ? s[t - off] : 0;
    __syncthreads();
    s[t] += u;
    __syncthreads();
  }
  if (t < nblk) bsums[t] = s[t] - v;  // exclusive
  if (t == nblk - 1) rowptr[N] = s[t];
}

__global__ void k_scan3(const int* __restrict__ deg, int N, const int* __restrict__ bsums,
                        int* __restrict__ rowptr, int* __restrict__ cursor,
                        float* __restrict__ dinv) {
  __shared__ int s[256];
  int gid = blockIdx.x * 256 + threadIdx.x;
  int v = (gid < N) ? deg[gid] : 0;
  s[threadIdx.x] = v;
  __syncthreads();
  for (int off = 1; off < 256; off <<= 1) {
    int t = (threadIdx.x >= off) ? s[threadIdx.x - off] : 0;
    __syncthreads();
    s[threadIdx.x] += t;
    __syncthreads();
  }
  if (gid < N) {
    int ex = bsums[blockIdx.x] + s[threadIdx.x] - v;
    rowptr[gid] = ex;
    cursor[gid] = ex;
    dinv[gid] = rsqrtf((float)v);
  }
}

__global__ void k_fill(const int* __restrict__ ei, int E, int N,
                       int* __restrict__ cursor, int* __restrict__ csr) {
  int e = blockIdx.x * blockDim.x + threadIdx.x;
  if (e >= E + N) return;
  int src, dst;
  if (e < E) { src = ei[e]; dst = ei[E + e]; } else { src = dst = e - E; }
  int pos = atomicAdd(&cursor[dst], 1);
  csr[pos] = src;
}

// ---------------- weight prep (fragment layouts) ----------------
// merged: proj_W -> WtPF  and  gat_W -> Wt2F (head-mean 0.25 folded)
__global__ void k_wprep(const float* __restrict__ Wp, const float* __restrict__ Wg,
                        unsigned short* __restrict__ WtPF,
                        unsigned short* __restrict__ Wt2F) {
  int idx = blockIdx.x * 256 + threadIdx.x;
  if (idx < INDIM * HID) {
    int k = idx >> 7, c = idx & 127;
    WtPF[fidx(c, k, INDIM)] = f2b(Wp[idx]);
    return;
  }
  idx -= INDIM * HID;
  if (idx >= NGAT * HID * HEADS * HID) return;
  int l = idx / (HID * HEADS * HID);
  int rem = idx - l * HID * HEADS * HID;
  int k = rem >> 9;
  int cc = rem & 511;
  int hh = cc >> 7, c = cc & 127;
  Wt2F[(size_t)l * (HID * HEADS * HID) + fidx(c, hh * HID + k, HEADS * HID)] =
      f2b(Wg[idx] * 0.25f);
}

// w_s[l][h][k] = sum_c gat_W[l][k][h*128+c] * att_src[l][h][c]  (and w_d)
__global__ void k_wvec(const float* __restrict__ W, const float* __restrict__ atts,
                       const float* __restrict__ attd, float* __restrict__ w_s,
                       float* __restrict__ w_d) {
  int lane = threadIdx.x & 63;
  int idx = blockIdx.x * 4 + (threadIdx.x >> 6);
  if (idx >= NGAT * HEADS * HID) return;
  int l = idx / (HEADS * HID);
  int rem = idx - l * (HEADS * HID);
  int hh = rem >> 7, k = rem & 127;
  const float2 w2 = *(const float2*)(W + ((size_t)(l * HID + k)) * (HEADS * HID) +
                                     hh * HID + lane * 2);
  const float2 s2 = *(const float2*)(atts + (size_t)(l * HEADS + hh) * HID + lane * 2);
  const float2 d2 = *(const float2*)(attd + (size_t)(l * HEADS + hh) * HID + lane * 2);
  float ps = w2.x * s2.x + w2.y * s2.y;
  float pd = w2.x * d2.x + w2.y * d2.y;
  ps = wsum(ps);
  pd = wsum(pd);
  if (lane == 0) { w_s[idx] = ps; w_d[idx] = pd; }
}

// ---------------- projection GEMM + fused layer-0 attention logits ----------------
// A (fp32 x) staged through LDS in fragment layout. Writes bf16 hb only.
__global__ __launch_bounds__(256) void k_mm(
    const float* __restrict__ x, const unsigned short* __restrict__ WtPF,
    const float* __restrict__ bias, const float* __restrict__ ws0,
    const float* __restrict__ wd0, unsigned short* __restrict__ hb,
    float* __restrict__ a_s, float* __restrict__ a_d, int Mreal) {
  __shared__ unsigned short As[64 * INDIM];  // 32 KB, fragment layout
  const int wid = threadIdx.x >> 6;
  const int lane = threadIdx.x & 63;
  const int l15 = lane & 15;
  const int g = lane >> 4;
  const int row0 = blockIdx.x * 64 + wid * 16;
#pragma unroll
  for (int i = 0; i < 8; ++i) {
    int p = threadIdx.x + 256 * i;
    int nl = p >> 5, kc = p & 31;
    int grow = blockIdx.x * 64 + nl;
    uint4 pk = make_uint4(0, 0, 0, 0);
    if (grow < Mreal) {
      const float* ap = x + (size_t)grow * INDIM + kc * 8;
      float4 u = *(const float4*)ap;
      float4 v = *(const float4*)(ap + 4);
      pk.x = (unsigned)f2b(u.x) | ((unsigned)f2b(u.y) << 16);
      pk.y = (unsigned)f2b(u.z) | ((unsigned)f2b(u.w) << 16);
      pk.z = (unsigned)f2b(v.x) | ((unsigned)f2b(v.y) << 16);
      pk.w = (unsigned)f2b(v.z) | ((unsigned)f2b(v.w) << 16);
    }
    *(uint4*)&As[((nl >> 4) * 8 + (kc >> 2)) * 512 + (((kc & 3) * 16 + (nl & 15)) << 3)] = pk;
  }
  __syncthreads();
  f32x4 acc[8] = {};
  const unsigned short* Bp = WtPF + lane * 8;
  for (int kb = 0; kb < 8; ++kb) {
    short8 af = *(const short8*)&As[(wid * 8 + kb) * 512 + lane * 8];
    short8 bfr[8];
#pragma unroll
    for (int ni = 0; ni < 8; ++ni)
      bfr[ni] = *(const short8*)(Bp + (size_t)(ni * 8 + kb) * 512);
#pragma unroll
    for (int ni = 0; ni < 8; ++ni)
      acc[ni] = __builtin_amdgcn_mfma_f32_16x16x32_bf16(af, bfr[ni], acc[ni], 0, 0, 0);
  }
#pragma unroll
  for (int r = 0; r < 4; ++r) {
    const int row = row0 + g * 4 + r;
    unsigned short* hbr = hb + (size_t)row * HID;
    float yv[8];
#pragma unroll
    for (int ni = 0; ni < 8; ++ni) {
      const int c = ni * 16 + l15;
      yv[ni] = acc[ni][r] + bias[c];
      hbr[c] = f2b(yv[ni]);
    }
    float ps[4], pd[4];
#pragma unroll
    for (int h4 = 0; h4 < 4; ++h4) {
      float pv = 0.f, qv = 0.f;
#pragma unroll
      for (int ni = 0; ni < 8; ++ni) {
        const int c = h4 * HID + ni * 16 + l15;
        pv = fmaf(yv[ni], ws0[c], pv);
        qv = fmaf(yv[ni], wd0[c], qv);
      }
#pragma unroll
      for (int m = 1; m < 16; m <<= 1) {
        pv += __shfl_xor(pv, m, 64);
        qv += __shfl_xor(qv, m, 64);
      }
      ps[h4] = pv;
      pd[h4] = qv;
    }
    if (l15 == 0) {
      *(float4*)(a_s + (size_t)row * 4) = make_float4(ps[0], ps[1], ps[2], ps[3]);
      *(float4*)(a_d + (size_t)row * 4) = make_float4(pd[0], pd[1], pd[2], pd[3]);
    }
  }
}

// ---------------- GAT aggregation into fragment-layout aggF ----------------
// TWO waves per node (halved serial gather chain). Waves 2k,2k+1 co-own node k:
// both run the 16-lane-group softmax prologue (identical, deterministic); each
// writes/gathers only its 32-edge half. Half-1 publishes acc via LDS; half-0
// combines and stores. deg>64 fallback: half-0 runs the full-wave path alone.
__global__ __launch_bounds__(256) void k_agg2(
    const int* __restrict__ rowptr, const int* __restrict__ csr,
    const unsigned short* __restrict__ hb, const float* __restrict__ a_s,
    const float* __restrict__ a_d, unsigned short* __restrict__ aggF, int N) {
  __shared__ int s_lds[4][32];
  __shared__ float al_lds[4][4][36];  // stride 36: 4 head-groups -> distinct banks
  __shared__ float red[2][64][8];     // half-1 partials (one-time 8-way conflict ok)
  int lane = threadIdx.x & 63;
  int wid = threadIdx.x >> 6;
  int n = blockIdx.x * 2 + (wid >> 1);
  const int half = wid & 1;
  const int g = lane >> 4;
  const int l15 = lane & 15;
  const bool valid = n < N;  // n < MPAD always (grid = MPAD/2)
  int beg = 0, end = 0, deg = 0;
  if (valid) {
    beg = rowptr[n];
    end = rowptr[n + 1];
    deg = end - beg;
  }
  const unsigned short* hbase = hb + l15 * 8;
  float acc[8] = {};
  float f[8];
  if (valid && deg <= 64) {
    // --- full softmax prologue (both halves compute identically) ---
    const float ad = a_d[n * 4 + g];
    int sj[4];
    float ex[4];
    float mymax = -3e38f;
#pragma unroll
    for (int j = 0; j < 4; ++j) {
      int e = beg + l15 + 16 * j;
      bool v = e < end;
      int s = v ? csr[e] : 0;
      sj[j] = s;
      float Lv = v ? lk2(a_s[s * 4 + g] + ad) : -3e38f;
      ex[j] = Lv;
      mymax = fmaxf(mymax, Lv);
    }
#pragma unroll
    for (int m = 1; m < 16; m <<= 1) mymax = fmaxf(mymax, __shfl_xor(mymax, m, 64));
    float mysum = 0.f;
#pragma unroll
    for (int j = 0; j < 4; ++j) {
      ex[j] = exp2f(ex[j] - mymax);  // invalid -> 0
      mysum += ex[j];
    }
#pragma unroll
    for (int m = 1; m < 16; m <<= 1) mysum += __shfl_xor(mysum, m, 64);
    float r = 1.f / mysum;
    // write only my half's alphas/srcs (edges half*32 .. half*32+31)
#pragma unroll
    for (int jj = 0; jj < 2; ++jj) {
      int j = half * 2 + jj;
      int i = l15 + 16 * jj;
      al_lds[wid][g][i] = ex[j] * r;
      if (g == 0) s_lds[wid][i] = sj[j];
    }
    asm volatile("s_waitcnt lgkmcnt(0)" ::: "memory");
    const int* sw = s_lds[wid];
    const float* aw = al_lds[wid][g];
    int myc = deg - half * 32;
    myc = myc < 0 ? 0 : (myc > 32 ? 32 : myc);
    int nIter = (myc + 3) >> 2;
    for (int it = 0; it < nIter; ++it) {
      int4 s4 = *(const int4*)(sw + it * 4);
      float4 a4 = *(const float4*)(aw + it * 4);
      uint4 r0 = *(const uint4*)(hbase + (size_t)s4.x * HID);
      uint4 r1 = *(const uint4*)(hbase + (size_t)s4.y * HID);
      uint4 r2 = *(const uint4*)(hbase + (size_t)s4.z * HID);
      uint4 r3 = *(const uint4*)(hbase + (size_t)s4.w * HID);
      unp8(r0, f);
#pragma unroll
      for (int j = 0; j < 8; ++j) acc[j] = fmaf(a4.x, f[j], acc[j]);
      unp8(r1, f);
#pragma unroll
      for (int j = 0; j < 8; ++j) acc[j] = fmaf(a4.y, f[j], acc[j]);
      unp8(r2, f);
#pragma unroll
      for (int j = 0; j < 8; ++j) acc[j] = fmaf(a4.z, f[j], acc[j]);
      unp8(r3, f);
#pragma unroll
      for (int j = 0; j < 8; ++j) acc[j] = fmaf(a4.w, f[j], acc[j]);
    }
  } else if (valid && half == 0) {
    // rare fallback (deg > 64): half-0 wave does the whole node
    const float4 adv = *(const float4*)(a_d + (size_t)n * 4);
    float m0 = -3e38f, m1 = -3e38f, m2 = -3e38f, m3 = -3e38f;
    for (int e = beg + lane; e < end; e += 64) {
      int s = csr[e];
      const float4 asv = *(const float4*)(a_s + (size_t)s * 4);
      m0 = fmaxf(m0, lk2(asv.x + adv.x));
      m1 = fmaxf(m1, lk2(asv.y + adv.y));
      m2 = fmaxf(m2, lk2(asv.z + adv.z));
      m3 = fmaxf(m3, lk2(asv.w + adv.w));
    }
    m0 = wmax(m0); m1 = wmax(m1); m2 = wmax(m2); m3 = wmax(m3);
    float d0 = 0.f, d1 = 0.f, d2 = 0.f, d3 = 0.f;
    for (int e = beg + lane; e < end; e += 64) {
      int s = csr[e];
      const float4 asv = *(const float4*)(a_s + (size_t)s * 4);
      d0 += exp2f(lk2(asv.x + adv.x) - m0);
      d1 += exp2f(lk2(asv.y + adv.y) - m1);
      d2 += exp2f(lk2(asv.z + adv.z) - m2);
      d3 += exp2f(lk2(asv.w + adv.w) - m3);
    }
    float r0 = 1.f / wsum(d0);
    float r1 = 1.f / wsum(d1);
    float r2 = 1.f / wsum(d2);
    float r3 = 1.f / wsum(d3);
    for (int sb = beg; sb < end; sb += 64) {
      int e = sb + lane;
      bool val = e < end;
      int s = csr[val ? e : end - 1];
      const float4 asv = *(const float4*)(a_s + (size_t)s * 4);
      float q0 = val ? exp2f(lk2(asv.x + adv.x) - m0) * r0 : 0.f;
      float q1 = val ? exp2f(lk2(asv.y + adv.y) - m1) * r1 : 0.f;
      float q2 = val ? exp2f(lk2(asv.z + adv.z) - m2) * r2 : 0.f;
      float q3 = val ? exp2f(lk2(asv.w + adv.w) - m3) * r3 : 0.f;
      int cnt = min(64, end - sb);
      for (int i = 0; i < cnt; ++i) {
        int si = __shfl(s, i, 64);
        float c0 = __shfl(q0, i, 64), c1 = __shfl(q1, i, 64);
        float c2 = __shfl(q2, i, 64), c3 = __shfl(q3, i, 64);
        uint4 hv = *(const uint4*)(hbase + (size_t)si * HID);
        float bi = sel4(c0, c1, c2, c3, g);
        unp8(hv, f);
#pragma unroll
        for (int j = 0; j < 8; ++j) acc[j] = fmaf(bi, f[j], acc[j]);
      }
    }
  }
  // combine halves via LDS (unconditional barrier)
  const int pair = wid >> 1;
  if (half == 1) {
#pragma unroll
    for (int j = 0; j < 8; ++j) red[pair][lane][j] = acc[j];
  }
  __syncthreads();
  if (half == 0) {
#pragma unroll
    for (int j = 0; j < 8; ++j) acc[j] += red[pair][lane][j];
    uint4 pk;
    pk.x = (unsigned)f2b(acc[0]) | ((unsigned)f2b(acc[1]) << 16);
    pk.y = (unsigned)f2b(acc[2]) | ((unsigned)f2b(acc[3]) << 16);
    pk.z = (unsigned)f2b(acc[4]) | ((unsigned)f2b(acc[5]) << 16);
    pk.w = (unsigned)f2b(acc[6]) | ((unsigned)f2b(acc[7]) << 16);
    size_t oaddr = ((size_t)(n >> 4) * 16 + (g * 4 + (l15 >> 2))) * 512 +
                   (((l15 & 3) * 16 + (n & 15)) << 3);
    *(uint4*)(aggF + oaddr) = pk;  // pad rows (n>=N): acc==0 -> zeros
  }
}

// ---------------- post-agg GEMM, K-split across waves ----------------
// Block = 16 rows; wave w computes kb = 4w..4w+3 partial; LDS reduce; epilogue
// bias+LN+ReLU+residual(bf16) + fused att (ATT=1) or xwd (ATT=2).
template <int ATT>
__global__ __launch_bounds__(256) void k_mm2(
    const unsigned short* __restrict__ aggF, const unsigned short* __restrict__ Bt,
    const float* __restrict__ bias, const float* __restrict__ gamma,
    const float* __restrict__ beta, const float* __restrict__ wsn,
    const float* __restrict__ wdn, unsigned short* __restrict__ hb,
    float* __restrict__ a_s, float* __restrict__ a_d,
    const float* __restrict__ dinvp, float* __restrict__ xwd) {
  __shared__ float red[4][16][132];  // pad 132 -> 2-way banks (free)
  const int wid = threadIdx.x >> 6;
  const int lane = threadIdx.x & 63;
  const int l15 = lane & 15;
  const int g = lane >> 4;
  const int row0 = blockIdx.x * 16;
  f32x4 acc[8] = {};
  const unsigned short* Ap = aggF + (size_t)blockIdx.x * 16 * 512 + lane * 8;
  const unsigned short* Bp = Bt + lane * 8;
#pragma unroll
  for (int kq = 0; kq < 4; ++kq) {
    const int kb = wid * 4 + kq;
    short8 a0 = *(const short8*)(Ap + (size_t)kb * 512);
    short8 bfr[8];
#pragma unroll
    for (int ni = 0; ni < 8; ++ni)
      bfr[ni] = *(const short8*)(Bp + (size_t)(ni * 16 + kb) * 512);
#pragma unroll
    for (int ni = 0; ni < 8; ++ni)
      acc[ni] = __builtin_amdgcn_mfma_f32_16x16x32_bf16(a0, bfr[ni], acc[ni], 0, 0, 0);
  }
#pragma unroll
  for (int ni = 0; ni < 8; ++ni)
#pragma unroll
    for (int r = 0; r < 4; ++r)
      red[wid][g * 4 + r][ni * 16 + l15] = acc[ni][r];
  __syncthreads();
  const int row_l = threadIdx.x >> 4;
  const int cg = threadIdx.x & 15;
  const int c0 = cg * 8;
  const int row = row0 + row_l;
  float y[8];
#pragma unroll
  for (int j = 0; j < 8; ++j)
    y[j] = ((red[0][row_l][c0 + j] + red[1][row_l][c0 + j]) +
            (red[2][row_l][c0 + j] + red[3][row_l][c0 + j])) + bias[c0 + j];
  float s = 0.f;
#pragma unroll
  for (int j = 0; j < 8; ++j) s += y[j];
#pragma unroll
  for (int m = 1; m < 16; m <<= 1) s += __shfl_xor(s, m, 64);
  float mu = s * (1.f / 128.f);
  float q = 0.f;
#pragma unroll
  for (int j = 0; j < 8; ++j) {
    float dd = y[j] - mu;
    q += dd * dd;
  }
#pragma unroll
  for (int m = 1; m < 16; m <<= 1) q += __shfl_xor(q, m, 64);
  float rstd = rsqrtf(q * (1.f / 128.f) + LN_EPS);
  unsigned short* hbr = hb + (size_t)row * HID;
  uint4 hv = *(const uint4*)(hbr + c0);
  float res[8];
  unp8(hv, res);
  float yv[8];
#pragma unroll
  for (int j = 0; j < 8; ++j) {
    float t = (y[j] - mu) * rstd * gamma[c0 + j] + beta[c0 + j];
    yv[j] = fmaxf(t, 0.f) + res[j];
  }
  uint4 pk;
  pk.x = (unsigned)f2b(yv[0]) | ((unsigned)f2b(yv[1]) << 16);
  pk.y = (unsigned)f2b(yv[2]) | ((unsigned)f2b(yv[3]) << 16);
  pk.z = (unsigned)f2b(yv[4]) | ((unsigned)f2b(yv[5]) << 16);
  pk.w = (unsigned)f2b(yv[6]) | ((unsigned)f2b(yv[7]) << 16);
  *(uint4*)(hbr + c0) = pk;
  if (ATT == 1) {
    float ps[4], pd[4];
#pragma unroll
    for (int h4 = 0; h4 < 4; ++h4) {
      float pv = 0.f, qv = 0.f;
#pragma unroll
      for (int j = 0; j < 8; ++j) {
        const int c = h4 * HID + c0 + j;
        pv = fmaf(yv[j], wsn[c], pv);
        qv = fmaf(yv[j], wdn[c], qv);
      }
#pragma unroll
      for (int m = 1; m < 16; m <<= 1) {
        pv += __shfl_xor(pv, m, 64);
        qv += __shfl_xor(qv, m, 64);
      }
      ps[h4] = pv;
      pd[h4] = qv;
    }
    if (cg == 0) {
      *(float4*)(a_s + (size_t)row * 4) = make_float4(ps[0], ps[1], ps[2], ps[3]);
      *(float4*)(a_d + (size_t)row * 4) = make_float4(pd[0], pd[1], pd[2], pd[3]);
    }
  } else {
    float pv = 0.f;
#pragma unroll
    for (int j = 0; j < 8; ++j) pv = fmaf(yv[j], wsn[c0 + j], pv);
#pragma unroll
    for (int m = 1; m < 16; m <<= 1) pv += __shfl_xor(pv, m, 64);
    if (cg == 0) xwd[row] = pv * dinvp[row];  // pad rows: garbage, never read
  }
}

// ---------------- GCN head: out[n] = sigmoid(dinv[n] * sum xwd[src] + b) ------
__global__ __launch_bounds__(256) void k_gcn(const int* __restrict__ rowptr,
                                             const int* __restrict__ csr,
                                             const float* __restrict__ xwd,
                                             const float* __restrict__ dinv,
                                             const float* __restrict__ gcn_b,
                                             float* __restrict__ out, int N) {
  int n = blockIdx.x * blockDim.x + threadIdx.x;
  if (n >= N) return;
  float acc = 0.f;
  int beg = rowptr[n], end = rowptr[n + 1];
  int e = beg;
  for (; e + 4 <= end; e += 4) {
    int s0 = csr[e], s1 = csr[e + 1], s2 = csr[e + 2], s3 = csr[e + 3];
    float v0 = xwd[s0], v1 = xwd[s1], v2 = xwd[s2], v3 = xwd[s3];
    acc += (v0 + v1) + (v2 + v3);
  }
  for (; e < end; ++e) acc += xwd[csr[e]];
  float z = acc * dinv[n] + gcn_b[0];
  out[n] = 1.f / (1.f + expf(-z));
}

extern "C" void kernel_launch(void* const* d_in, const int* in_sizes, int n_in,
                              void* d_out, int out_size, void* d_ws, size_t ws_size,
                              hipStream_t stream) {
  const float* x = (const float*)d_in[0];
  const int* ei = (const int*)d_in[1];
  const float* proj_W = (const float*)d_in[2];
  const float* proj_b = (const float*)d_in[3];
  const float* gat_W = (const float*)d_in[4];
  const float* gat_as = (const float*)d_in[5];
  const float* gat_ad = (const float*)d_in[6];
  const float* gat_bias = (const float*)d_in[7];
  const float* ln_g = (const float*)d_in[8];
  const float* ln_b = (const float*)d_in[9];
  const float* gcn_W = (const float*)d_in[10];
  const float* gcn_b = (const float*)d_in[11];
  float* out = (float*)d_out;

  const int N = in_sizes[0] / INDIM;  // 40000
  const int E = in_sizes[1] / 2;      // 320000
  const int TOT = E + N;

  size_t off = 0;
  auto alloc = [&](size_t bytes) {
    void* p = (char*)d_ws + off;
    off += (bytes + 255) & ~(size_t)255;
    return p;
  };
  unsigned short* hb = (unsigned short*)alloc((size_t)MPAD * HID * 2);
  unsigned short* aggF = (unsigned short*)alloc((size_t)MPAD * HEADS * HID * 2);
  unsigned short* WtPF = (unsigned short*)alloc((size_t)HID * INDIM * 2);
  unsigned short* Wt2F = (unsigned short*)alloc((size_t)NGAT * HID * HEADS * HID * 2);
  float* w_s = (float*)alloc((size_t)NGAT * HEADS * HID * 4);
  float* w_d = (float*)alloc((size_t)NGAT * HEADS * HID * 4);
  float* a_s = (float*)alloc((size_t)MPAD * HEADS * 4);
  float* a_d = (float*)alloc((size_t)MPAD * HEADS * 4);
  int* deg = (int*)alloc((size_t)N * 4);
  int* rowptr = (int*)alloc((size_t)(N + 1) * 4);
  int* cursor = (int*)alloc((size_t)N * 4);
  int* csr = (int*)alloc((size_t)TOT * 4);
  int* bsums = (int*)alloc(1024);
  float* dinv = (float*)alloc((size_t)MPAD * 4);  // MPAD: k_mm2<2> pad reads in-bounds
  float* xwd = (float*)alloc((size_t)MPAD * 4);
  (void)ws_size;

  const int NBLK = (N + 255) / 256;
  const int EBLK = (TOT + 255) / 256;

  // CSR build
  hipMemsetAsync(deg, 0, (size_t)N * 4, stream);
  k_deg<<<EBLK, 256, 0, stream>>>(ei, E, N, deg);
  k_scan1<<<NBLK, 256, 0, stream>>>(deg, N, bsums);
  k_scan2<<<1, 256, 0, stream>>>(bsums, NBLK, rowptr, N);
  k_scan3<<<NBLK, 256, 0, stream>>>(deg, N, bsums, rowptr, cursor, dinv);
  k_fill<<<EBLK, 256, 0, stream>>>(ei, E, N, cursor, csr);

  // weight prep (fragment layouts)
  const int WPN = INDIM * HID + NGAT * HID * HEADS * HID;
  k_wprep<<<(WPN + 255) / 256, 256, 0, stream>>>(proj_W, gat_W, WtPF, Wt2F);
  k_wvec<<<(NGAT * HEADS * HID + 3) / 4, 256, 0, stream>>>(gat_W, gat_as, gat_ad, w_s, w_d);

  // projection (reads fp32 x via LDS staging) + layer-0 attention logits
  k_mm<<<MPAD / 64, 256, 0, stream>>>(x, WtPF, proj_b, w_s, w_d, hb, a_s, a_d, N);

  for (int i = 0; i < NGAT; ++i) {
    k_agg2<<<MPAD / 2, 256, 0, stream>>>(rowptr, csr, hb, a_s, a_d, aggF, N);
    if (i < NGAT - 1) {
      k_mm2<1><<<MPAD / 16, 256, 0, stream>>>(
          aggF, Wt2F + (size_t)i * HID * HEADS * HID, gat_bias + (size_t)i * HID,
          ln_g + (size_t)i * HID, ln_b + (size_t)i * HID,
          w_s + (size_t)(i + 1) * HEADS * HID, w_d + (size_t)(i + 1) * HEADS * HID,
          hb, a_s, a_d, nullptr, nullptr);
    } else {
      k_mm2<2><<<MPAD / 16, 256, 0, stream>>>(
          aggF, Wt2F + (size_t)i * HID * HEADS * HID, gat_bias + (size_t)i * HID,
          ln_g + (size_t)i * HID, ln_b + (size_t)i * HID, gcn_W, nullptr,
          hb, nullptr, nullptr, dinv, xwd);
    }
  }

  // GCN head
  k_gcn<<<NBLK, 256, 0, stream>>>(rowptr, csr, xwd, dinv, gcn_b, out, N);
}

// Round 16
// 247.281 us; speedup vs baseline: 1.1929x; 1.1929x over previous
//
#include <hip/hip_runtime.h>
#include <math.h>

#define INDIM 256
#define HID 128
#define HEADS 4
#define NGAT 3
#define LN_EPS 1e-5f
#define SLOPE 0.2f
#define MPAD 40064  // 313 * 128; N=40000 is divisible by 16
#define LOG2E 1.4426950408889634f

typedef __attribute__((ext_vector_type(8))) short short8;
typedef __attribute__((ext_vector_type(4))) float f32x4;

__device__ inline float wsum(float v) {
#pragma unroll
  for (int m = 1; m < 64; m <<= 1) v += __shfl_xor(v, m, 64);
  return v;
}
__device__ inline float wmax(float v) {
#pragma unroll
  for (int m = 1; m < 64; m <<= 1) v = fmaxf(v, __shfl_xor(v, m, 64));
  return v;
}
// leaky_relu then scale to exp2 domain
__device__ inline float lk2(float v) { return fmaxf(v, SLOPE * v) * LOG2E; }
// static-select (broadcast BEFORE select — round-5 lesson)
__device__ inline float sel4(float a0, float a1, float a2, float a3, int i) {
  float lo = (i & 1) ? a1 : a0;
  float hi = (i & 1) ? a3 : a2;
  return (i & 2) ? hi : lo;
}

__device__ inline unsigned short f2b(float f) {
  unsigned u = __float_as_uint(f);
  unsigned r = (u + 0x7FFFu + ((u >> 16) & 1u)) >> 16;
  return (unsigned short)r;
}
__device__ inline float b2f(unsigned short b) {
  return __uint_as_float(((unsigned)b) << 16);
}
__device__ inline void unp8(const uint4 v, float f[8]) {
  f[0] = __uint_as_float(v.x << 16);
  f[1] = __uint_as_float(v.x & 0xFFFF0000u);
  f[2] = __uint_as_float(v.y << 16);
  f[3] = __uint_as_float(v.y & 0xFFFF0000u);
  f[4] = __uint_as_float(v.z << 16);
  f[5] = __uint_as_float(v.z & 0xFFFF0000u);
  f[6] = __uint_as_float(v.w << 16);
  f[7] = __uint_as_float(v.w & 0xFFFF0000u);
}

// MFMA fragment layout index: element (row,k) of a [rows][K] bf16 matrix.
__device__ __host__ inline size_t fidx(int row, int k, int K) {
  return ((size_t)(row >> 4) * (K >> 5) + (k >> 5)) * 512 +
         ((((k >> 3) & 3) * 16 + (row & 15)) << 3) + (k & 7);
}

// ---------------- CSR construction ----------------
__global__ void k_deg(const int* __restrict__ ei, int E, int N, int* __restrict__ deg) {
  int e = blockIdx.x * blockDim.x + threadIdx.x;
  if (e >= E + N) return;
  int dst = (e < E) ? ei[E + e] : (e - E);
  atomicAdd(&deg[dst], 1);
}

__global__ void k_scan1(const int* __restrict__ deg, int N, int* __restrict__ bsums) {
  __shared__ int s[256];
  int gid = blockIdx.x * 256 + threadIdx.x;
  s[threadIdx.x] = (gid < N) ? deg[gid] : 0;
  __syncthreads();
  for (int off = 128; off > 0; off >>= 1) {
    if (threadIdx.x < off) s[threadIdx.x] += s[threadIdx.x + off];
    __syncthreads();
  }
  if (threadIdx.x == 0) bsums[blockIdx.x] = s[0];
}

// one-block parallel scan over block sums (nblk <= 256)
__global__ void k_scan2(int* __restrict__ bsums, int nblk, int* __restrict__ rowptr, int N) {
  __shared__ int s[256];
  int t = threadIdx.x;
  int v = (t < nblk) ? bsums[t] : 0;
  s[t] = v;
  __syncthreads();
  for (int off = 1; off < 256; off <<= 1) {
    int u = (t >= off) ? s[t - off] : 0;
    __syncthreads();
    s[t] += u;
    __syncthreads();
  }
  if (t < nblk) bsums[t] = s[t] - v;  // exclusive
  if (t == nblk - 1) rowptr[N] = s[t];
}

__global__ void k_scan3(const int* __restrict__ deg, int N, const int* __restrict__ bsums,
                        int* __restrict__ rowptr, int* __restrict__ cursor,
                        float* __restrict__ dinv) {
  __shared__ int s[256];
  int gid = blockIdx.x * 256 + threadIdx.x;
  int v = (gid < N) ? deg[gid] : 0;
  s[threadIdx.x] = v;
  __syncthreads();
  for (int off = 1; off < 256; off <<= 1) {
    int t = (threadIdx.x >= off) ? s[threadIdx.x - off] : 0;
    __syncthreads();
    s[threadIdx.x] += t;
    __syncthreads();
  }
  if (gid < N) {
    int ex = bsums[blockIdx.x] + s[threadIdx.x] - v;
    rowptr[gid] = ex;
    cursor[gid] = ex;
    dinv[gid] = rsqrtf((float)v);
  }
}

__global__ void k_fill(const int* __restrict__ ei, int E, int N,
                       int* __restrict__ cursor, int* __restrict__ csr) {
  int e = blockIdx.x * blockDim.x + threadIdx.x;
  if (e >= E + N) return;
  int src, dst;
  if (e < E) { src = ei[e]; dst = ei[E + e]; } else { src = dst = e - E; }
  int pos = atomicAdd(&cursor[dst], 1);
  csr[pos] = src;
}

// ---------------- weight prep (fragment layouts) ----------------
// merged: proj_W -> WtPF  and  gat_W -> Wt2F (head-mean 0.25 folded)
__global__ void k_wprep(const float* __restrict__ Wp, const float* __restrict__ Wg,
                        unsigned short* __restrict__ WtPF,
                        unsigned short* __restrict__ Wt2F) {
  int idx = blockIdx.x * 256 + threadIdx.x;
  if (idx < INDIM * HID) {
    int k = idx >> 7, c = idx & 127;
    WtPF[fidx(c, k, INDIM)] = f2b(Wp[idx]);
    return;
  }
  idx -= INDIM * HID;
  if (idx >= NGAT * HID * HEADS * HID) return;
  int l = idx / (HID * HEADS * HID);
  int rem = idx - l * HID * HEADS * HID;
  int k = rem >> 9;
  int cc = rem & 511;
  int hh = cc >> 7, c = cc & 127;
  Wt2F[(size_t)l * (HID * HEADS * HID) + fidx(c, hh * HID + k, HEADS * HID)] =
      f2b(Wg[idx] * 0.25f);
}

// w_s[l][h][k] = sum_c gat_W[l][k][h*128+c] * att_src[l][h][c]  (and w_d)
__global__ void k_wvec(const float* __restrict__ W, const float* __restrict__ atts,
                       const float* __restrict__ attd, float* __restrict__ w_s,
                       float* __restrict__ w_d) {
  int lane = threadIdx.x & 63;
  int idx = blockIdx.x * 4 + (threadIdx.x >> 6);
  if (idx >= NGAT * HEADS * HID) return;
  int l = idx / (HEADS * HID);
  int rem = idx - l * (HEADS * HID);
  int hh = rem >> 7, k = rem & 127;
  const float2 w2 = *(const float2*)(W + ((size_t)(l * HID + k)) * (HEADS * HID) +
                                     hh * HID + lane * 2);
  const float2 s2 = *(const float2*)(atts + (size_t)(l * HEADS + hh) * HID + lane * 2);
  const float2 d2 = *(const float2*)(attd + (size_t)(l * HEADS + hh) * HID + lane * 2);
  float ps = w2.x * s2.x + w2.y * s2.y;
  float pd = w2.x * d2.x + w2.y * d2.y;
  ps = wsum(ps);
  pd = wsum(pd);
  if (lane == 0) { w_s[idx] = ps; w_d[idx] = pd; }
}

// ---------------- projection GEMM + fused layer-0 attention logits ----------------
// A (fp32 x) staged through LDS in fragment layout. Writes bf16 hb only.
__global__ __launch_bounds__(256) void k_mm(
    const float* __restrict__ x, const unsigned short* __restrict__ WtPF,
    const float* __restrict__ bias, const float* __restrict__ ws0,
    const float* __restrict__ wd0, unsigned short* __restrict__ hb,
    float* __restrict__ a_s, float* __restrict__ a_d, int Mreal) {
  __shared__ unsigned short As[64 * INDIM];  // 32 KB, fragment layout
  const int wid = threadIdx.x >> 6;
  const int lane = threadIdx.x & 63;
  const int l15 = lane & 15;
  const int g = lane >> 4;
  const int row0 = blockIdx.x * 64 + wid * 16;
#pragma unroll
  for (int i = 0; i < 8; ++i) {
    int p = threadIdx.x + 256 * i;
    int nl = p >> 5, kc = p & 31;
    int grow = blockIdx.x * 64 + nl;
    uint4 pk = make_uint4(0, 0, 0, 0);
    if (grow < Mreal) {
      const float* ap = x + (size_t)grow * INDIM + kc * 8;
      float4 u = *(const float4*)ap;
      float4 v = *(const float4*)(ap + 4);
      pk.x = (unsigned)f2b(u.x) | ((unsigned)f2b(u.y) << 16);
      pk.y = (unsigned)f2b(u.z) | ((unsigned)f2b(u.w) << 16);
      pk.z = (unsigned)f2b(v.x) | ((unsigned)f2b(v.y) << 16);
      pk.w = (unsigned)f2b(v.z) | ((unsigned)f2b(v.w) << 16);
    }
    *(uint4*)&As[((nl >> 4) * 8 + (kc >> 2)) * 512 + (((kc & 3) * 16 + (nl & 15)) << 3)] = pk;
  }
  __syncthreads();
  f32x4 acc[8] = {};
  const unsigned short* Bp = WtPF + lane * 8;
  for (int kb = 0; kb < 8; ++kb) {
    short8 af = *(const short8*)&As[(wid * 8 + kb) * 512 + lane * 8];
    short8 bfr[8];
#pragma unroll
    for (int ni = 0; ni < 8; ++ni)
      bfr[ni] = *(const short8*)(Bp + (size_t)(ni * 8 + kb) * 512);
#pragma unroll
    for (int ni = 0; ni < 8; ++ni)
      acc[ni] = __builtin_amdgcn_mfma_f32_16x16x32_bf16(af, bfr[ni], acc[ni], 0, 0, 0);
  }
#pragma unroll
  for (int r = 0; r < 4; ++r) {
    const int row = row0 + g * 4 + r;
    unsigned short* hbr = hb + (size_t)row * HID;
    float yv[8];
#pragma unroll
    for (int ni = 0; ni < 8; ++ni) {
      const int c = ni * 16 + l15;
      yv[ni] = acc[ni][r] + bias[c];
      hbr[c] = f2b(yv[ni]);
    }
    float ps[4], pd[4];
#pragma unroll
    for (int h4 = 0; h4 < 4; ++h4) {
      float pv = 0.f, qv = 0.f;
#pragma unroll
      for (int ni = 0; ni < 8; ++ni) {
        const int c = h4 * HID + ni * 16 + l15;
        pv = fmaf(yv[ni], ws0[c], pv);
        qv = fmaf(yv[ni], wd0[c], qv);
      }
#pragma unroll
      for (int m = 1; m < 16; m <<= 1) {
        pv += __shfl_xor(pv, m, 64);
        qv += __shfl_xor(qv, m, 64);
      }
      ps[h4] = pv;
      pd[h4] = qv;
    }
    if (l15 == 0) {
      *(float4*)(a_s + (size_t)row * 4) = make_float4(ps[0], ps[1], ps[2], ps[3]);
      *(float4*)(a_d + (size_t)row * 4) = make_float4(pd[0], pd[1], pd[2], pd[3]);
    }
  }
}

// ---------------- GAT aggregation into fragment-layout aggF ----------------
// Wave per node. 16-lane-group softmax prologue, 4-edge gather loop
// (VGPR-lean, 0 bank conflicts — the measured-best round-14 version; wave-pair
// split regressed via red[][][8] 16-way conflicts + doubled prologue).
__global__ __launch_bounds__(256) void k_agg2(
    const int* __restrict__ rowptr, const int* __restrict__ csr,
    const unsigned short* __restrict__ hb, const float* __restrict__ a_s,
    const float* __restrict__ a_d, unsigned short* __restrict__ aggF, int N) {
  __shared__ int s_lds[4][64];
  __shared__ float al_lds[4][4][68];  // stride 68: head-groups hit distinct banks
  int lane = threadIdx.x & 63;
  int wid = threadIdx.x >> 6;
  int n = blockIdx.x * 4 + wid;
  if (n >= MPAD) return;
  const int g = lane >> 4;
  const int l15 = lane & 15;
  size_t oaddr = ((size_t)(n >> 4) * 16 + (g * 4 + (l15 >> 2))) * 512 +
                 (((l15 & 3) * 16 + (n & 15)) << 3);
  if (n >= N) {
    *(uint4*)(aggF + oaddr) = make_uint4(0, 0, 0, 0);
    return;
  }
  int beg = rowptr[n], end = rowptr[n + 1];
  int deg = end - beg;
  const unsigned short* hbase = hb + l15 * 8;
  float acc[8] = {};
  float f[8];
  if (deg <= 64) {
    const float ad = a_d[n * 4 + g];
    int sj[4];
    float ex[4];
    float mymax = -3e38f;
#pragma unroll
    for (int j = 0; j < 4; ++j) {
      int e = beg + l15 + 16 * j;
      bool v = e < end;
      int s = v ? csr[e] : 0;
      sj[j] = s;
      float Lv = v ? lk2(a_s[s * 4 + g] + ad) : -3e38f;
      ex[j] = Lv;
      mymax = fmaxf(mymax, Lv);
    }
#pragma unroll
    for (int m = 1; m < 16; m <<= 1) mymax = fmaxf(mymax, __shfl_xor(mymax, m, 64));
    float mysum = 0.f;
#pragma unroll
    for (int j = 0; j < 4; ++j) {
      ex[j] = exp2f(ex[j] - mymax);
      mysum += ex[j];
    }
#pragma unroll
    for (int m = 1; m < 16; m <<= 1) mysum += __shfl_xor(mysum, m, 64);
    float r = 1.f / mysum;
#pragma unroll
    for (int j = 0; j < 4; ++j) {
      int i = l15 + 16 * j;
      al_lds[wid][g][i] = ex[j] * r;
      if (g == 0) s_lds[wid][i] = sj[j];
    }
    asm volatile("s_waitcnt lgkmcnt(0)" ::: "memory");
    const int* sw = s_lds[wid];
    const float* aw = al_lds[wid][g];
    int nIter = (deg + 3) >> 2;
    for (int it = 0; it < nIter; ++it) {
      int4 s4 = *(const int4*)(sw + it * 4);
      float4 a4 = *(const float4*)(aw + it * 4);
      uint4 r0 = *(const uint4*)(hbase + (size_t)s4.x * HID);
      uint4 r1 = *(const uint4*)(hbase + (size_t)s4.y * HID);
      uint4 r2 = *(const uint4*)(hbase + (size_t)s4.z * HID);
      uint4 r3 = *(const uint4*)(hbase + (size_t)s4.w * HID);
      unp8(r0, f);
#pragma unroll
      for (int j = 0; j < 8; ++j) acc[j] = fmaf(a4.x, f[j], acc[j]);
      unp8(r1, f);
#pragma unroll
      for (int j = 0; j < 8; ++j) acc[j] = fmaf(a4.y, f[j], acc[j]);
      unp8(r2, f);
#pragma unroll
      for (int j = 0; j < 8; ++j) acc[j] = fmaf(a4.z, f[j], acc[j]);
      unp8(r3, f);
#pragma unroll
      for (int j = 0; j < 8; ++j) acc[j] = fmaf(a4.w, f[j], acc[j]);
    }
  } else {
    const float4 adv = *(const float4*)(a_d + (size_t)n * 4);
    float m0 = -3e38f, m1 = -3e38f, m2 = -3e38f, m3 = -3e38f;
    for (int e = beg + lane; e < end; e += 64) {
      int s = csr[e];
      const float4 asv = *(const float4*)(a_s + (size_t)s * 4);
      m0 = fmaxf(m0, lk2(asv.x + adv.x));
      m1 = fmaxf(m1, lk2(asv.y + adv.y));
      m2 = fmaxf(m2, lk2(asv.z + adv.z));
      m3 = fmaxf(m3, lk2(asv.w + adv.w));
    }
    m0 = wmax(m0); m1 = wmax(m1); m2 = wmax(m2); m3 = wmax(m3);
    float d0 = 0.f, d1 = 0.f, d2 = 0.f, d3 = 0.f;
    for (int e = beg + lane; e < end; e += 64) {
      int s = csr[e];
      const float4 asv = *(const float4*)(a_s + (size_t)s * 4);
      d0 += exp2f(lk2(asv.x + adv.x) - m0);
      d1 += exp2f(lk2(asv.y + adv.y) - m1);
      d2 += exp2f(lk2(asv.z + adv.z) - m2);
      d3 += exp2f(lk2(asv.w + adv.w) - m3);
    }
    float r0 = 1.f / wsum(d0);
    float r1 = 1.f / wsum(d1);
    float r2 = 1.f / wsum(d2);
    float r3 = 1.f / wsum(d3);
    for (int sb = beg; sb < end; sb += 64) {
      int e = sb + lane;
      bool val = e < end;
      int s = csr[val ? e : end - 1];
      const float4 asv = *(const float4*)(a_s + (size_t)s * 4);
      float q0 = val ? exp2f(lk2(asv.x + adv.x) - m0) * r0 : 0.f;
      float q1 = val ? exp2f(lk2(asv.y + adv.y) - m1) * r1 : 0.f;
      float q2 = val ? exp2f(lk2(asv.z + adv.z) - m2) * r2 : 0.f;
      float q3 = val ? exp2f(lk2(asv.w + adv.w) - m3) * r3 : 0.f;
      int cnt = min(64, end - sb);
      for (int i = 0; i < cnt; ++i) {
        int si = __shfl(s, i, 64);
        float c0 = __shfl(q0, i, 64), c1 = __shfl(q1, i, 64);
        float c2 = __shfl(q2, i, 64), c3 = __shfl(q3, i, 64);
        uint4 hv = *(const uint4*)(hbase + (size_t)si * HID);
        float bi = sel4(c0, c1, c2, c3, g);
        unp8(hv, f);
#pragma unroll
        for (int j = 0; j < 8; ++j) acc[j] = fmaf(bi, f[j], acc[j]);
      }
    }
  }
  uint4 pk;
  pk.x = (unsigned)f2b(acc[0]) | ((unsigned)f2b(acc[1]) << 16);
  pk.y = (unsigned)f2b(acc[2]) | ((unsigned)f2b(acc[3]) << 16);
  pk.z = (unsigned)f2b(acc[4]) | ((unsigned)f2b(acc[5]) << 16);
  pk.w = (unsigned)f2b(acc[6]) | ((unsigned)f2b(acc[7]) << 16);
  *(uint4*)(aggF + oaddr) = pk;
}

// ---------------- post-agg GEMM, K-split across waves ----------------
// Block = 16 rows; wave w computes kb = 4w..4w+3 partial; LDS reduce; epilogue
// bias+LN+ReLU+residual(bf16) + fused att (ATT=1) or xwd (ATT=2).
template <int ATT>
__global__ __launch_bounds__(256) void k_mm2(
    const unsigned short* __restrict__ aggF, const unsigned short* __restrict__ Bt,
    const float* __restrict__ bias, const float* __restrict__ gamma,
    const float* __restrict__ beta, const float* __restrict__ wsn,
    const float* __restrict__ wdn, unsigned short* __restrict__ hb,
    float* __restrict__ a_s, float* __restrict__ a_d,
    const float* __restrict__ dinvp, float* __restrict__ xwd) {
  __shared__ float red[4][16][132];  // pad 132 -> 2-way banks (free)
  const int wid = threadIdx.x >> 6;
  const int lane = threadIdx.x & 63;
  const int l15 = lane & 15;
  const int g = lane >> 4;
  const int row0 = blockIdx.x * 16;
  f32x4 acc[8] = {};
  const unsigned short* Ap = aggF + (size_t)blockIdx.x * 16 * 512 + lane * 8;
  const unsigned short* Bp = Bt + lane * 8;
#pragma unroll
  for (int kq = 0; kq < 4; ++kq) {
    const int kb = wid * 4 + kq;
    short8 a0 = *(const short8*)(Ap + (size_t)kb * 512);
    short8 bfr[8];
#pragma unroll
    for (int ni = 0; ni < 8; ++ni)
      bfr[ni] = *(const short8*)(Bp + (size_t)(ni * 16 + kb) * 512);
#pragma unroll
    for (int ni = 0; ni < 8; ++ni)
      acc[ni] = __builtin_amdgcn_mfma_f32_16x16x32_bf16(a0, bfr[ni], acc[ni], 0, 0, 0);
  }
#pragma unroll
  for (int ni = 0; ni < 8; ++ni)
#pragma unroll
    for (int r = 0; r < 4; ++r)
      red[wid][g * 4 + r][ni * 16 + l15] = acc[ni][r];
  __syncthreads();
  const int row_l = threadIdx.x >> 4;
  const int cg = threadIdx.x & 15;
  const int c0 = cg * 8;
  const int row = row0 + row_l;
  float y[8];
#pragma unroll
  for (int j = 0; j < 8; ++j)
    y[j] = ((red[0][row_l][c0 + j] + red[1][row_l][c0 + j]) +
            (red[2][row_l][c0 + j] + red[3][row_l][c0 + j])) + bias[c0 + j];
  float s = 0.f;
#pragma unroll
  for (int j = 0; j < 8; ++j) s += y[j];
#pragma unroll
  for (int m = 1; m < 16; m <<= 1) s += __shfl_xor(s, m, 64);
  float mu = s * (1.f / 128.f);
  float q = 0.f;
#pragma unroll
  for (int j = 0; j < 8; ++j) {
    float dd = y[j] - mu;
    q += dd * dd;
  }
#pragma unroll
  for (int m = 1; m < 16; m <<= 1) q += __shfl_xor(q, m, 64);
  float rstd = rsqrtf(q * (1.f / 128.f) + LN_EPS);
  unsigned short* hbr = hb + (size_t)row * HID;
  uint4 hv = *(const uint4*)(hbr + c0);
  float res[8];
  unp8(hv, res);
  float yv[8];
#pragma unroll
  for (int j = 0; j < 8; ++j) {
    float t = (y[j] - mu) * rstd * gamma[c0 + j] + beta[c0 + j];
    yv[j] = fmaxf(t, 0.f) + res[j];
  }
  uint4 pk;
  pk.x = (unsigned)f2b(yv[0]) | ((unsigned)f2b(yv[1]) << 16);
  pk.y = (unsigned)f2b(yv[2]) | ((unsigned)f2b(yv[3]) << 16);
  pk.z = (unsigned)f2b(yv[4]) | ((unsigned)f2b(yv[5]) << 16);
  pk.w = (unsigned)f2b(yv[6]) | ((unsigned)f2b(yv[7]) << 16);
  *(uint4*)(hbr + c0) = pk;
  if (ATT == 1) {
    float ps[4], pd[4];
#pragma unroll
    for (int h4 = 0; h4 < 4; ++h4) {
      float pv = 0.f, qv = 0.f;
#pragma unroll
      for (int j = 0; j < 8; ++j) {
        const int c = h4 * HID + c0 + j;
        pv = fmaf(yv[j], wsn[c], pv);
        qv = fmaf(yv[j], wdn[c], qv);
      }
#pragma unroll
      for (int m = 1; m < 16; m <<= 1) {
        pv += __shfl_xor(pv, m, 64);
        qv += __shfl_xor(qv, m, 64);
      }
      ps[h4] = pv;
      pd[h4] = qv;
    }
    if (cg == 0) {
      *(float4*)(a_s + (size_t)row * 4) = make_float4(ps[0], ps[1], ps[2], ps[3]);
      *(float4*)(a_d + (size_t)row * 4) = make_float4(pd[0], pd[1], pd[2], pd[3]);
    }
  } else {
    float pv = 0.f;
#pragma unroll
    for (int j = 0; j < 8; ++j) pv = fmaf(yv[j], wsn[c0 + j], pv);
#pragma unroll
    for (int m = 1; m < 16; m <<= 1) pv += __shfl_xor(pv, m, 64);
    if (cg == 0) xwd[row] = pv * dinvp[row];  // pad rows: garbage, never read
  }
}

// ---------------- GCN head: out[n] = sigmoid(dinv[n] * sum xwd[src] + b) ------
__global__ __launch_bounds__(256) void k_gcn(const int* __restrict__ rowptr,
                                             const int* __restrict__ csr,
                                             const float* __restrict__ xwd,
                                             const float* __restrict__ dinv,
                                             const float* __restrict__ gcn_b,
                                             float* __restrict__ out, int N) {
  int n = blockIdx.x * blockDim.x + threadIdx.x;
  if (n >= N) return;
  float acc = 0.f;
  int beg = rowptr[n], end = rowptr[n + 1];
  int e = beg;
  for (; e + 4 <= end; e += 4) {
    int s0 = csr[e], s1 = csr[e + 1], s2 = csr[e + 2], s3 = csr[e + 3];
    float v0 = xwd[s0], v1 = xwd[s1], v2 = xwd[s2], v3 = xwd[s3];
    acc += (v0 + v1) + (v2 + v3);
  }
  for (; e < end; ++e) acc += xwd[csr[e]];
  float z = acc * dinv[n] + gcn_b[0];
  out[n] = 1.f / (1.f + expf(-z));
}

extern "C" void kernel_launch(void* const* d_in, const int* in_sizes, int n_in,
                              void* d_out, int out_size, void* d_ws, size_t ws_size,
                              hipStream_t stream) {
  const float* x = (const float*)d_in[0];
  const int* ei = (const int*)d_in[1];
  const float* proj_W = (const float*)d_in[2];
  const float* proj_b = (const float*)d_in[3];
  const float* gat_W = (const float*)d_in[4];
  const float* gat_as = (const float*)d_in[5];
  const float* gat_ad = (const float*)d_in[6];
  const float* gat_bias = (const float*)d_in[7];
  const float* ln_g = (const float*)d_in[8];
  const float* ln_b = (const float*)d_in[9];
  const float* gcn_W = (const float*)d_in[10];
  const float* gcn_b = (const float*)d_in[11];
  float* out = (float*)d_out;

  const int N = in_sizes[0] / INDIM;  // 40000
  const int E = in_sizes[1] / 2;      // 320000
  const int TOT = E + N;

  size_t off = 0;
  auto alloc = [&](size_t bytes) {
    void* p = (char*)d_ws + off;
    off += (bytes + 255) & ~(size_t)255;
    return p;
  };
  unsigned short* hb = (unsigned short*)alloc((size_t)MPAD * HID * 2);
  unsigned short* aggF = (unsigned short*)alloc((size_t)MPAD * HEADS * HID * 2);
  unsigned short* WtPF = (unsigned short*)alloc((size_t)HID * INDIM * 2);
  unsigned short* Wt2F = (unsigned short*)alloc((size_t)NGAT * HID * HEADS * HID * 2);
  float* w_s = (float*)alloc((size_t)NGAT * HEADS * HID * 4);
  float* w_d = (float*)alloc((size_t)NGAT * HEADS * HID * 4);
  float* a_s = (float*)alloc((size_t)MPAD * HEADS * 4);
  float* a_d = (float*)alloc((size_t)MPAD * HEADS * 4);
  int* deg = (int*)alloc((size_t)N * 4);
  int* rowptr = (int*)alloc((size_t)(N + 1) * 4);
  int* cursor = (int*)alloc((size_t)N * 4);
  int* csr = (int*)alloc((size_t)TOT * 4);
  int* bsums = (int*)alloc(1024);
  float* dinv = (float*)alloc((size_t)MPAD * 4);  // MPAD: k_mm2<2> pad reads in-bounds
  float* xwd = (float*)alloc((size_t)MPAD * 4);
  (void)ws_size;

  const int NBLK = (N + 255) / 256;
  const int EBLK = (TOT + 255) / 256;

  // CSR build
  hipMemsetAsync(deg, 0, (size_t)N * 4, stream);
  k_deg<<<EBLK, 256, 0, stream>>>(ei, E, N, deg);
  k_scan1<<<NBLK, 256, 0, stream>>>(deg, N, bsums);
  k_scan2<<<1, 256, 0, stream>>>(bsums, NBLK, rowptr, N);
  k_scan3<<<NBLK, 256, 0, stream>>>(deg, N, bsums, rowptr, cursor, dinv);
  k_fill<<<EBLK, 256, 0, stream>>>(ei, E, N, cursor, csr);

  // weight prep (fragment layouts)
  const int WPN = INDIM * HID + NGAT * HID * HEADS * HID;
  k_wprep<<<(WPN + 255) / 256, 256, 0, stream>>>(proj_W, gat_W, WtPF, Wt2F);
  k_wvec<<<(NGAT * HEADS * HID + 3) / 4, 256, 0, stream>>>(gat_W, gat_as, gat_ad, w_s, w_d);

  // projection (reads fp32 x via LDS staging) + layer-0 attention logits
  k_mm<<<MPAD / 64, 256, 0, stream>>>(x, WtPF, proj_b, w_s, w_d, hb, a_s, a_d, N);

  for (int i = 0; i < NGAT; ++i) {
    k_agg2<<<MPAD / 4, 256, 0, stream>>>(rowptr, csr, hb, a_s, a_d, aggF, N);
    if (i < NGAT - 1) {
      k_mm2<1><<<MPAD / 16, 256, 0, stream>>>(
          aggF, Wt2F + (size_t)i * HID * HEADS * HID, gat_bias + (size_t)i * HID,
          ln_g + (size_t)i * HID, ln_b + (size_t)i * HID,
          w_s + (size_t)(i + 1) * HEADS * HID, w_d + (size_t)(i + 1) * HEADS * HID,
          hb, a_s, a_d, nullptr, nullptr);
    } else {
      k_mm2<2><<<MPAD / 16, 256, 0, stream>>>(
          aggF, Wt2F + (size_t)i * HID * HEADS * HID, gat_bias + (size_t)i * HID,
          ln_g + (size_t)i * HID, ln_b + (size_t)i * HID, gcn_W, nullptr,
          hb, nullptr, nullptr, dinv, xwd);
    }
  }

  // GCN head
  k_gcn<<<NBLK, 256, 0, stream>>>(rowptr, csr, xwd, dinv, gcn_b, out, N);
}